// Round 1
// baseline (421.005 us; speedup 1.0000x reference)
//
#include <hip/hip_runtime.h>
#include <hip/hip_bf16.h>
#include <math.h>

// Problem constants (fixed by setup_inputs)
#define N_NODES 1024
#define F_DIM   1024
#define H_DIM   512
#define E_EDGES 32768
#define B_GRAPHS 16
#define OUT_DIM 10
#define FH_DIM  1536
#define EPS 1e-5f
#define MH_C_F 0.8673250705840776f
#define INV_SQRT2 0.70710678118654752440f

// ---------------- K1: Haar split + attention gate -> h, agg=h ----------------
__global__ __launch_bounds__(256) void k_h(const float* __restrict__ x,
                                           const float* __restrict__ watt,
                                           float* __restrict__ h,
                                           float* __restrict__ agg) {
    int idx = blockIdx.x * 256 + threadIdx.x;          // 0 .. N*H-1
    float2 p = ((const float2*)x)[idx];                // x[n][2j], x[n][2j+1]
    float lo = (p.x + p.y) * INV_SQRT2;
    float hi = (p.x - p.y) * INV_SQRT2;
    float t  = lo * watt[0] + hi * watt[1];
    float sc = 1.0f / (1.0f + __expf(-t));
    float hv = sc * lo + (1.0f - sc) * hi;
    h[idx] = hv;
    agg[idx] = hv;
}

// ---------------- K2: edge scatter-add (agg[dst] += h[src]) ----------------
__global__ __launch_bounds__(256) void k_scatter(const float* __restrict__ h,
                                                 const int* __restrict__ src,
                                                 const int* __restrict__ dst,
                                                 float* __restrict__ agg) {
    int e = blockIdx.x;
    int s = src[e], d = dst[e];
    int j = threadIdx.x;
    unsafeAtomicAdd(&agg[d * H_DIM + j],       h[s * H_DIM + j]);
    unsafeAtomicAdd(&agg[d * H_DIM + j + 256], h[s * H_DIM + j + 256]);
}

// ---------------- K2b: sagg = silu(agg) ----------------
__global__ __launch_bounds__(256) void k_silu(const float* __restrict__ agg,
                                              float* __restrict__ sagg) {
    int idx = blockIdx.x * 256 + threadIdx.x;
    float a = agg[idx];
    sagg[idx] = a / (1.0f + __expf(-a));
}

// ---------------- K3: fused wavelet + base: vb[n,o] = wav + base ----------------
// wav[n,o] = MH_C * sum_i (1-xs^2)*exp(-0.5 xs^2)*ww[o,i],  xs = agg[n,i]*is - trans*is
// base[n,o] = sum_i silu(agg[n,i]) * bw[o,i]
#define TN 64
#define TO 32
#define KI 32
__global__ __launch_bounds__(256) void k_wavelet(const float* __restrict__ agg,
                                                 const float* __restrict__ sagg,
                                                 const float* __restrict__ trans,
                                                 const float* __restrict__ scale,
                                                 const float* __restrict__ ww,
                                                 const float* __restrict__ bw,
                                                 float* __restrict__ vb) {
    __shared__ float sA[KI * TN];   // [i][n] transposed
    __shared__ float sS[KI * TN];
    __shared__ float sTF[KI * TO];  // [i][o] transposed; trans*invscale
    __shared__ float sIS[KI * TO];  // invscale
    __shared__ float sWW[KI * TO];
    __shared__ float sBW[KI * TO];

    const int t  = threadIdx.x;
    const int n0 = blockIdx.x * TN;
    const int o0 = blockIdx.y * TO;
    const int tn = t & 15;      // n-group (4 n each)
    const int to = t >> 4;      // o-group (2 o each)
    const int nl = tn * 4;
    const int ol = to * 2;

    float accw[4][2] = {};
    float accb[4][2] = {};

    for (int i0 = 0; i0 < H_DIM; i0 += KI) {
        __syncthreads();
        // stage n-side: 64 rows x KI cols (as float4), transpose into [i][n]
        #pragma unroll
        for (int v = 0; v < 2; ++v) {
            int idx = v * 256 + t;           // 0..511
            int c = idx & 7, r = idx >> 3;   // c: f4-col (i), r: row (n)
            const int g = (n0 + r) * H_DIM + i0 + c * 4;
            float4 a4 = *(const float4*)&agg[g];
            float4 s4 = *(const float4*)&sagg[g];
            int ib = c * 4;
            sA[(ib + 0) * TN + r] = a4.x; sA[(ib + 1) * TN + r] = a4.y;
            sA[(ib + 2) * TN + r] = a4.z; sA[(ib + 3) * TN + r] = a4.w;
            sS[(ib + 0) * TN + r] = s4.x; sS[(ib + 1) * TN + r] = s4.y;
            sS[(ib + 2) * TN + r] = s4.z; sS[(ib + 3) * TN + r] = s4.w;
        }
        // stage o-side: 32 rows x KI cols
        {
            int c = t & 7, r = t >> 3;       // r: 0..31 (o)
            const int g = (o0 + r) * H_DIM + i0 + c * 4;
            float4 t4 = *(const float4*)&trans[g];
            float4 c4 = *(const float4*)&scale[g];
            float4 w4 = *(const float4*)&ww[g];
            float4 b4 = *(const float4*)&bw[g];
            float i0v = 1.0f / c4.x, i1v = 1.0f / c4.y, i2v = 1.0f / c4.z, i3v = 1.0f / c4.w;
            int ib = c * 4;
            sIS[(ib + 0) * TO + r] = i0v; sIS[(ib + 1) * TO + r] = i1v;
            sIS[(ib + 2) * TO + r] = i2v; sIS[(ib + 3) * TO + r] = i3v;
            sTF[(ib + 0) * TO + r] = t4.x * i0v; sTF[(ib + 1) * TO + r] = t4.y * i1v;
            sTF[(ib + 2) * TO + r] = t4.z * i2v; sTF[(ib + 3) * TO + r] = t4.w * i3v;
            sWW[(ib + 0) * TO + r] = w4.x; sWW[(ib + 1) * TO + r] = w4.y;
            sWW[(ib + 2) * TO + r] = w4.z; sWW[(ib + 3) * TO + r] = w4.w;
            sBW[(ib + 0) * TO + r] = b4.x; sBW[(ib + 1) * TO + r] = b4.y;
            sBW[(ib + 2) * TO + r] = b4.z; sBW[(ib + 3) * TO + r] = b4.w;
        }
        __syncthreads();
        #pragma unroll 4
        for (int i = 0; i < KI; ++i) {
            float4 a  = *(const float4*)&sA[i * TN + nl];
            float4 s  = *(const float4*)&sS[i * TN + nl];
            float2 tf = *(const float2*)&sTF[i * TO + ol];
            float2 iv = *(const float2*)&sIS[i * TO + ol];
            float2 w2 = *(const float2*)&sWW[i * TO + ol];
            float2 b2 = *(const float2*)&sBW[i * TO + ol];
            float av[4] = {a.x, a.y, a.z, a.w};
            float sv[4] = {s.x, s.y, s.z, s.w};
            float tfv[2] = {tf.x, tf.y}, ivv[2] = {iv.x, iv.y};
            float wv[2]  = {w2.x, w2.y}, bvv[2] = {b2.x, b2.y};
            #pragma unroll
            for (int nn = 0; nn < 4; ++nn) {
                #pragma unroll
                for (int oo = 0; oo < 2; ++oo) {
                    float xs = av[nn] * ivv[oo] - tfv[oo];
                    float x2 = xs * xs;
                    float u  = 1.0f - x2;
                    float e  = __expf(-0.5f * x2);
                    accw[nn][oo] += u * e * wv[oo];
                    accb[nn][oo] += sv[nn] * bvv[oo];
                }
            }
        }
    }
    #pragma unroll
    for (int nn = 0; nn < 4; ++nn) {
        float2 out;
        out.x = MH_C_F * accw[nn][0] + accb[nn][0];
        out.y = MH_C_F * accw[nn][1] + accb[nn][1];
        *(float2*)&vb[(n0 + nl + nn) * H_DIM + o0 + ol] = out;
    }
}

// ---------------- K4/K5: per-column mean + folded BN scale ----------------
// mode 0: single BN (for x columns).  mode 1: bn(bn(.)) then bn inside z (vb columns).
__global__ __launch_bounds__(256) void k_colstats(const float* __restrict__ srcp,
                                                  int ncols, int mode,
                                                  float* __restrict__ mu_out,
                                                  float* __restrict__ S_out) {
    int c0 = blockIdx.x * 64;
    int t = threadIdx.x;
    int c = c0 + (t & 63);
    int r0 = t >> 6;
    float s = 0.f, s2 = 0.f;
    for (int n = r0; n < N_NODES; n += 4) {
        float v = srcp[n * ncols + c];
        s += v; s2 += v * v;
    }
    __shared__ float sh1[256], sh2[256];
    sh1[t] = s; sh2[t] = s2;
    __syncthreads();
    if (t < 64) {
        s  = sh1[t] + sh1[t + 64] + sh1[t + 128] + sh1[t + 192];
        s2 = sh2[t] + sh2[t + 64] + sh2[t + 128] + sh2[t + 192];
        float mu  = s * (1.0f / N_NODES);
        float var = s2 * (1.0f / N_NODES) - mu * mu;
        if (var < 0.f) var = 0.f;
        float S;
        if (mode == 0) {
            S = 1.0f / sqrtf(var + EPS);
        } else {
            float s1v = 1.0f / sqrtf(var + EPS);
            float v1  = var * s1v * s1v;          // var/(var+eps)
            float s2v = 1.0f / sqrtf(v1 + EPS);
            float v2  = v1 * s2v * s2v;
            float s3v = 1.0f / sqrtf(v2 + EPS);
            S = s1v * s2v * s3v;
        }
        mu_out[c] = mu;
        S_out[c]  = S;
    }
}

// ---------------- K6a: graph ranges (batch is sorted) ----------------
__global__ __launch_bounds__(256) void k_ranges(const int* __restrict__ batch,
                                                int* __restrict__ gstart,
                                                int* __restrict__ gcnt) {
    __shared__ int cnt_sh[B_GRAPHS];
    __shared__ int start_sh[B_GRAPHS];
    int t = threadIdx.x;
    if (t < B_GRAPHS) { cnt_sh[t] = 0; start_sh[t] = 0; }
    __syncthreads();
    for (int n = t; n < N_NODES; n += 256) {
        int b = batch[n];
        atomicAdd(&cnt_sh[b], 1);
        if (n == 0 || batch[n - 1] != b) start_sh[b] = n;
    }
    __syncthreads();
    if (t < B_GRAPHS) { gstart[t] = start_sh[t]; gcnt[t] = cnt_sh[t]; }
}

// ---------------- K6b: pooled[b,c] = (mean_b(col) - mu)*S ----------------
__global__ __launch_bounds__(256) void k_pool(const float* __restrict__ x,
                                              const float* __restrict__ vb,
                                              const int* __restrict__ gstart,
                                              const int* __restrict__ gcnt,
                                              const float* __restrict__ mux,
                                              const float* __restrict__ Sx,
                                              const float* __restrict__ muv,
                                              const float* __restrict__ Sv,
                                              float* __restrict__ pooled) {
    int b = blockIdx.y;
    int c = blockIdx.x * 256 + threadIdx.x;   // 0..1535
    int cnt = gcnt[b], st = gstart[b];
    float acc = 0.f;
    if (c < F_DIM) {
        for (int r = 0; r < cnt; ++r) acc += x[(st + r) * F_DIM + c];
    } else {
        int o = c - F_DIM;
        for (int r = 0; r < cnt; ++r) acc += vb[(st + r) * H_DIM + o];
    }
    float out = 0.f;
    if (cnt > 0) {
        float m = acc / (float)cnt;
        out = (c < F_DIM) ? (m - mux[c]) * Sx[c]
                          : (m - muv[c - F_DIM]) * Sv[c - F_DIM];
    }
    pooled[b * FH_DIM + c] = out;
}

// ---------------- K7: h1 = relu(pooled @ fc1_w^T + b1), one wave per (b,o) ----------------
__global__ __launch_bounds__(256) void k_fc1(const float* __restrict__ pooled,
                                             const float* __restrict__ w,
                                             const float* __restrict__ bias,
                                             float* __restrict__ h1) {
    int wid = (blockIdx.x * 256 + threadIdx.x) >> 6;   // 0..8191
    int lane = threadIdx.x & 63;
    int b = wid >> 9, o = wid & 511;
    const float* pr = pooled + b * FH_DIM;
    const float* wr = w + o * FH_DIM;
    float acc = 0.f;
    for (int k = lane; k < FH_DIM; k += 64) acc += pr[k] * wr[k];
    #pragma unroll
    for (int off = 32; off > 0; off >>= 1) acc += __shfl_down(acc, off);
    if (lane == 0) h1[b * H_DIM + o] = fmaxf(acc + bias[o], 0.f);
}

// ---------------- K8: out = h1 @ fc2_w^T + b2, one wave per (b,u) ----------------
__global__ __launch_bounds__(256) void k_fc2(const float* __restrict__ h1,
                                             const float* __restrict__ w,
                                             const float* __restrict__ bias,
                                             float* __restrict__ outp) {
    int wid = (blockIdx.x * 256 + threadIdx.x) >> 6;   // need 160
    int lane = threadIdx.x & 63;
    if (wid >= B_GRAPHS * OUT_DIM) return;
    int b = wid / OUT_DIM, u = wid % OUT_DIM;
    const float* hr = h1 + b * H_DIM;
    const float* wr = w + u * H_DIM;
    float acc = 0.f;
    for (int k = lane; k < H_DIM; k += 64) acc += hr[k] * wr[k];
    #pragma unroll
    for (int off = 32; off > 0; off >>= 1) acc += __shfl_down(acc, off);
    if (lane == 0) outp[b * OUT_DIM + u] = acc + bias[u];
}

extern "C" void kernel_launch(void* const* d_in, const int* in_sizes, int n_in,
                              void* d_out, int out_size, void* d_ws, size_t ws_size,
                              hipStream_t stream) {
    const float* x       = (const float*)d_in[0];
    const float* w_att   = (const float*)d_in[1];
    const float* wk_scale= (const float*)d_in[2];
    const float* wk_trans= (const float*)d_in[3];
    const float* wk_wav  = (const float*)d_in[4];
    const float* wk_base = (const float*)d_in[5];
    const float* fc1_w   = (const float*)d_in[6];
    const float* fc1_b   = (const float*)d_in[7];
    const float* fc2_w   = (const float*)d_in[8];
    const float* fc2_b   = (const float*)d_in[9];
    const int*   eidx    = (const int*)d_in[10];
    const int*   batch   = (const int*)d_in[11];
    float* outp = (float*)d_out;

    float* ws = (float*)d_ws;
    float* h      = ws;                        // 1024*512
    float* agg    = h + N_NODES * H_DIM;       // 1024*512
    float* sagg   = agg + N_NODES * H_DIM;     // 1024*512
    float* vb     = sagg + N_NODES * H_DIM;    // 1024*512
    float* muv    = vb + N_NODES * H_DIM;      // 512
    float* Sv     = muv + 512;                 // 512
    float* mux    = Sv + 512;                  // 1024
    float* Sx     = mux + 1024;                // 1024
    int*   gstart = (int*)(Sx + 1024);         // 16
    int*   gcnt   = gstart + 16;               // 16
    float* pooled = (float*)(gcnt + 16);       // 16*1536
    float* h1     = pooled + B_GRAPHS * FH_DIM;// 16*512

    const int* src = eidx;
    const int* dst = eidx + E_EDGES;

    k_h<<<(N_NODES * H_DIM) / 256, 256, 0, stream>>>(x, w_att, h, agg);
    k_scatter<<<E_EDGES, 256, 0, stream>>>(h, src, dst, agg);
    k_silu<<<(N_NODES * H_DIM) / 256, 256, 0, stream>>>(agg, sagg);
    {
        dim3 grid(N_NODES / TN, H_DIM / TO);
        k_wavelet<<<grid, 256, 0, stream>>>(agg, sagg, wk_trans, wk_scale,
                                            wk_wav, wk_base, vb);
    }
    k_colstats<<<H_DIM / 64, 256, 0, stream>>>(vb, H_DIM, 1, muv, Sv);
    k_colstats<<<F_DIM / 64, 256, 0, stream>>>(x, F_DIM, 0, mux, Sx);
    k_ranges<<<1, 256, 0, stream>>>(batch, gstart, gcnt);
    {
        dim3 grid(FH_DIM / 256, B_GRAPHS);
        k_pool<<<grid, 256, 0, stream>>>(x, vb, gstart, gcnt, mux, Sx, muv, Sv, pooled);
    }
    k_fc1<<<(B_GRAPHS * H_DIM * 64) / 256, 256, 0, stream>>>(pooled, fc1_w, fc1_b, h1);
    k_fc2<<<(B_GRAPHS * OUT_DIM * 64 + 255) / 256, 256, 0, stream>>>(h1, fc2_w, fc2_b, outp);
}

// Round 2
// 274.986 us; speedup vs baseline: 1.5310x; 1.5310x over previous
//
#include <hip/hip_runtime.h>
#include <hip/hip_bf16.h>
#include <math.h>

// Problem constants (fixed by setup_inputs)
#define N_NODES 1024
#define F_DIM   1024
#define H_DIM   512
#define E_EDGES 32768
#define B_GRAPHS 16
#define OUT_DIM 10
#define FH_DIM  1536
#define EPS 1e-5f
#define MH_C_F 0.8673250705840776f
#define INV_SQRT2 0.70710678118654752440f

// ---------------- K1: Haar split + attention gate -> h ----------------
__global__ __launch_bounds__(256) void k_h(const float* __restrict__ x,
                                           const float* __restrict__ watt,
                                           float* __restrict__ h) {
    int idx = blockIdx.x * 256 + threadIdx.x;          // 0 .. N*H-1
    float2 p = ((const float2*)x)[idx];                // x[n][2j], x[n][2j+1]
    float lo = (p.x + p.y) * INV_SQRT2;
    float hi = (p.x - p.y) * INV_SQRT2;
    float t  = lo * watt[0] + hi * watt[1];
    float sc = 1.0f / (1.0f + __expf(-t));
    h[idx] = sc * lo + (1.0f - sc) * hi;
}

// ---------------- edge bucketing (counting sort by dst) ----------------
__global__ __launch_bounds__(256) void k_zero_int(int* __restrict__ p, int n) {
    int i = blockIdx.x * 256 + threadIdx.x;
    if (i < n) p[i] = 0;
}

__global__ __launch_bounds__(256) void k_hist(const int* __restrict__ dst,
                                              int* __restrict__ deg) {
    int e = blockIdx.x * 256 + threadIdx.x;
    atomicAdd(&deg[dst[e]], 1);
}

__global__ __launch_bounds__(1024) void k_scan(const int* __restrict__ deg,
                                               int* __restrict__ start,
                                               int* __restrict__ cursor) {
    __shared__ int sh[N_NODES];
    int t = threadIdx.x;
    int d0 = deg[t];
    sh[t] = d0;
    __syncthreads();
    for (int off = 1; off < N_NODES; off <<= 1) {
        int v = (t >= off) ? sh[t - off] : 0;
        __syncthreads();
        sh[t] += v;
        __syncthreads();
    }
    int excl = sh[t] - d0;
    start[t] = excl;
    cursor[t] = excl;
}

__global__ __launch_bounds__(256) void k_fill(const int* __restrict__ src,
                                              const int* __restrict__ dst,
                                              int* __restrict__ cursor,
                                              int* __restrict__ elist) {
    int e = blockIdx.x * 256 + threadIdx.x;
    int slot = atomicAdd(&cursor[dst[e]], 1);
    elist[slot] = src[e];
}

// ---------------- K2: gather (atomic-free scatter-add) + fused SiLU ----------------
// agg[d] = h[d] + sum_{e: dst=d} h[src[e]];  sagg = silu(agg)
__global__ __launch_bounds__(256) void k_gather(const float* __restrict__ h,
                                                const int* __restrict__ start,
                                                const int* __restrict__ deg,
                                                const int* __restrict__ elist,
                                                float* __restrict__ agg,
                                                float* __restrict__ sagg) {
    int d = blockIdx.x;
    int t = threadIdx.x;
    int st = start[d], dg = deg[d];
    float a0 = h[d * H_DIM + t];
    float a1 = h[d * H_DIM + t + 256];
    for (int k = 0; k < dg; ++k) {
        int s = elist[st + k];
        a0 += h[s * H_DIM + t];
        a1 += h[s * H_DIM + t + 256];
    }
    agg[d * H_DIM + t]       = a0;
    agg[d * H_DIM + t + 256] = a1;
    sagg[d * H_DIM + t]       = a0 / (1.0f + __expf(-a0));
    sagg[d * H_DIM + t + 256] = a1 / (1.0f + __expf(-a1));
}

__global__ __launch_bounds__(256) void k_zero_f(float* __restrict__ p) {
    p[blockIdx.x * 256 + threadIdx.x] = 0.0f;
}

// ---------------- K3: fused wavelet + base, z-split over i ----------------
// vb[n,o] += MH_C * sum_i (1-xs^2)*exp(-0.5 xs^2)*ww[o,i] + sum_i silu(agg[n,i])*bw[o,i]
#define TN 64
#define TO 32
#define KI 32
#define ZSPLIT 4
#define ZLEN (H_DIM / ZSPLIT)   // 128
__global__ __launch_bounds__(256) void k_wavelet(const float* __restrict__ agg,
                                                 const float* __restrict__ sagg,
                                                 const float* __restrict__ trans,
                                                 const float* __restrict__ scale,
                                                 const float* __restrict__ ww,
                                                 const float* __restrict__ bw,
                                                 float* __restrict__ vb) {
    __shared__ float sA[KI * TN];   // [i][n] transposed
    __shared__ float sS[KI * TN];
    __shared__ float sTF[KI * TO];  // [i][o] transposed; trans*invscale
    __shared__ float sIS[KI * TO];  // invscale
    __shared__ float sWW[KI * TO];
    __shared__ float sBW[KI * TO];

    const int t  = threadIdx.x;
    const int n0 = blockIdx.x * TN;
    const int o0 = blockIdx.y * TO;
    const int z0 = blockIdx.z * ZLEN;
    const int tn = t & 15;      // n-group (4 n each)
    const int to = t >> 4;      // o-group (2 o each)
    const int nl = tn * 4;
    const int ol = to * 2;

    float accw[4][2] = {};
    float accb[4][2] = {};

    for (int i0 = z0; i0 < z0 + ZLEN; i0 += KI) {
        __syncthreads();
        // stage n-side: 64 rows x KI cols (as float4), transpose into [i][n]
        #pragma unroll
        for (int v = 0; v < 2; ++v) {
            int idx = v * 256 + t;           // 0..511
            int c = idx & 7, r = idx >> 3;   // c: f4-col (i), r: row (n)
            const int g = (n0 + r) * H_DIM + i0 + c * 4;
            float4 a4 = *(const float4*)&agg[g];
            float4 s4 = *(const float4*)&sagg[g];
            int ib = c * 4;
            sA[(ib + 0) * TN + r] = a4.x; sA[(ib + 1) * TN + r] = a4.y;
            sA[(ib + 2) * TN + r] = a4.z; sA[(ib + 3) * TN + r] = a4.w;
            sS[(ib + 0) * TN + r] = s4.x; sS[(ib + 1) * TN + r] = s4.y;
            sS[(ib + 2) * TN + r] = s4.z; sS[(ib + 3) * TN + r] = s4.w;
        }
        // stage o-side: 32 rows x KI cols
        {
            int c = t & 7, r = t >> 3;       // r: 0..31 (o)
            const int g = (o0 + r) * H_DIM + i0 + c * 4;
            float4 t4 = *(const float4*)&trans[g];
            float4 c4 = *(const float4*)&scale[g];
            float4 w4 = *(const float4*)&ww[g];
            float4 b4 = *(const float4*)&bw[g];
            float i0v = 1.0f / c4.x, i1v = 1.0f / c4.y, i2v = 1.0f / c4.z, i3v = 1.0f / c4.w;
            int ib = c * 4;
            sIS[(ib + 0) * TO + r] = i0v; sIS[(ib + 1) * TO + r] = i1v;
            sIS[(ib + 2) * TO + r] = i2v; sIS[(ib + 3) * TO + r] = i3v;
            sTF[(ib + 0) * TO + r] = t4.x * i0v; sTF[(ib + 1) * TO + r] = t4.y * i1v;
            sTF[(ib + 2) * TO + r] = t4.z * i2v; sTF[(ib + 3) * TO + r] = t4.w * i3v;
            sWW[(ib + 0) * TO + r] = w4.x; sWW[(ib + 1) * TO + r] = w4.y;
            sWW[(ib + 2) * TO + r] = w4.z; sWW[(ib + 3) * TO + r] = w4.w;
            sBW[(ib + 0) * TO + r] = b4.x; sBW[(ib + 1) * TO + r] = b4.y;
            sBW[(ib + 2) * TO + r] = b4.z; sBW[(ib + 3) * TO + r] = b4.w;
        }
        __syncthreads();
        #pragma unroll 4
        for (int i = 0; i < KI; ++i) {
            float4 a  = *(const float4*)&sA[i * TN + nl];
            float4 s  = *(const float4*)&sS[i * TN + nl];
            float2 tf = *(const float2*)&sTF[i * TO + ol];
            float2 iv = *(const float2*)&sIS[i * TO + ol];
            float2 w2 = *(const float2*)&sWW[i * TO + ol];
            float2 b2 = *(const float2*)&sBW[i * TO + ol];
            float av[4] = {a.x, a.y, a.z, a.w};
            float sv[4] = {s.x, s.y, s.z, s.w};
            float tfv[2] = {tf.x, tf.y}, ivv[2] = {iv.x, iv.y};
            float wv[2]  = {w2.x, w2.y}, bvv[2] = {b2.x, b2.y};
            #pragma unroll
            for (int nn = 0; nn < 4; ++nn) {
                #pragma unroll
                for (int oo = 0; oo < 2; ++oo) {
                    float xs = av[nn] * ivv[oo] - tfv[oo];
                    float x2 = xs * xs;
                    float u  = 1.0f - x2;
                    float e  = __expf(-0.5f * x2);
                    accw[nn][oo] += u * e * wv[oo];
                    accb[nn][oo] += sv[nn] * bvv[oo];
                }
            }
        }
    }
    #pragma unroll
    for (int nn = 0; nn < 4; ++nn) {
        int idx = (n0 + nl + nn) * H_DIM + o0 + ol;
        unsafeAtomicAdd(&vb[idx],     MH_C_F * accw[nn][0] + accb[nn][0]);
        unsafeAtomicAdd(&vb[idx + 1], MH_C_F * accw[nn][1] + accb[nn][1]);
    }
}

// ---------------- K4/K5: per-column mean + folded BN scale ----------------
// mode 0: single BN (x columns).  mode 1: triple-BN fold (vb columns).
__global__ __launch_bounds__(256) void k_colstats(const float* __restrict__ srcp,
                                                  int ncols, int mode,
                                                  float* __restrict__ mu_out,
                                                  float* __restrict__ S_out) {
    int c = blockIdx.x * 16 + (threadIdx.x & 15);
    int r0 = threadIdx.x >> 4;     // 0..15
    float s = 0.f, s2 = 0.f;
    for (int n = r0; n < N_NODES; n += 16) {
        float v = srcp[n * ncols + c];
        s += v; s2 += v * v;
    }
    __shared__ float sh1[256], sh2[256];
    int t = threadIdx.x;
    sh1[t] = s; sh2[t] = s2;
    __syncthreads();
    if (t < 16) {
        s = 0.f; s2 = 0.f;
        #pragma unroll
        for (int k = 0; k < 16; ++k) { s += sh1[t + k * 16]; s2 += sh2[t + k * 16]; }
        float mu  = s * (1.0f / N_NODES);
        float var = s2 * (1.0f / N_NODES) - mu * mu;
        if (var < 0.f) var = 0.f;
        float S;
        if (mode == 0) {
            S = 1.0f / sqrtf(var + EPS);
        } else {
            float s1v = 1.0f / sqrtf(var + EPS);
            float v1  = var * s1v * s1v;          // var/(var+eps)
            float s2v = 1.0f / sqrtf(v1 + EPS);
            float v2  = v1 * s2v * s2v;
            float s3v = 1.0f / sqrtf(v2 + EPS);
            S = s1v * s2v * s3v;
        }
        mu_out[c] = mu;
        S_out[c]  = S;
    }
}

// ---------------- K6a: graph ranges (batch is sorted) ----------------
__global__ __launch_bounds__(256) void k_ranges(const int* __restrict__ batch,
                                                int* __restrict__ gstart,
                                                int* __restrict__ gcnt) {
    __shared__ int cnt_sh[B_GRAPHS];
    __shared__ int start_sh[B_GRAPHS];
    int t = threadIdx.x;
    if (t < B_GRAPHS) { cnt_sh[t] = 0; start_sh[t] = 0; }
    __syncthreads();
    for (int n = t; n < N_NODES; n += 256) {
        int b = batch[n];
        atomicAdd(&cnt_sh[b], 1);
        if (n == 0 || batch[n - 1] != b) start_sh[b] = n;
    }
    __syncthreads();
    if (t < B_GRAPHS) { gstart[t] = start_sh[t]; gcnt[t] = cnt_sh[t]; }
}

// ---------------- K6b: pooled[b,c] = (mean_b(col) - mu)*S ----------------
__global__ __launch_bounds__(256) void k_pool(const float* __restrict__ x,
                                              const float* __restrict__ vb,
                                              const int* __restrict__ gstart,
                                              const int* __restrict__ gcnt,
                                              const float* __restrict__ mux,
                                              const float* __restrict__ Sx,
                                              const float* __restrict__ muv,
                                              const float* __restrict__ Sv,
                                              float* __restrict__ pooled) {
    int b = blockIdx.y;
    int c = blockIdx.x * 256 + threadIdx.x;   // 0..1535
    int cnt = gcnt[b], st = gstart[b];
    float acc = 0.f;
    if (c < F_DIM) {
        for (int r = 0; r < cnt; ++r) acc += x[(st + r) * F_DIM + c];
    } else {
        int o = c - F_DIM;
        for (int r = 0; r < cnt; ++r) acc += vb[(st + r) * H_DIM + o];
    }
    float out = 0.f;
    if (cnt > 0) {
        float m = acc / (float)cnt;
        out = (c < F_DIM) ? (m - mux[c]) * Sx[c]
                          : (m - muv[c - F_DIM]) * Sv[c - F_DIM];
    }
    pooled[b * FH_DIM + c] = out;
}

// ---------------- K7: h1 = relu(pooled @ fc1_w^T + b1), one wave per (b,o) ----------------
__global__ __launch_bounds__(256) void k_fc1(const float* __restrict__ pooled,
                                             const float* __restrict__ w,
                                             const float* __restrict__ bias,
                                             float* __restrict__ h1) {
    int wid = (blockIdx.x * 256 + threadIdx.x) >> 6;   // 0..8191
    int lane = threadIdx.x & 63;
    int b = wid >> 9, o = wid & 511;
    const float* pr = pooled + b * FH_DIM;
    const float* wr = w + o * FH_DIM;
    float acc = 0.f;
    for (int k = lane; k < FH_DIM; k += 64) acc += pr[k] * wr[k];
    #pragma unroll
    for (int off = 32; off > 0; off >>= 1) acc += __shfl_down(acc, off);
    if (lane == 0) h1[b * H_DIM + o] = fmaxf(acc + bias[o], 0.f);
}

// ---------------- K8: out = h1 @ fc2_w^T + b2, one wave per (b,u) ----------------
__global__ __launch_bounds__(256) void k_fc2(const float* __restrict__ h1,
                                             const float* __restrict__ w,
                                             const float* __restrict__ bias,
                                             float* __restrict__ outp) {
    int wid = (blockIdx.x * 256 + threadIdx.x) >> 6;
    int lane = threadIdx.x & 63;
    if (wid >= B_GRAPHS * OUT_DIM) return;
    int b = wid / OUT_DIM, u = wid % OUT_DIM;
    const float* hr = h1 + b * H_DIM;
    const float* wr = w + u * H_DIM;
    float acc = 0.f;
    for (int k = lane; k < H_DIM; k += 64) acc += hr[k] * wr[k];
    #pragma unroll
    for (int off = 32; off > 0; off >>= 1) acc += __shfl_down(acc, off);
    if (lane == 0) outp[b * OUT_DIM + u] = acc + bias[u];
}

extern "C" void kernel_launch(void* const* d_in, const int* in_sizes, int n_in,
                              void* d_out, int out_size, void* d_ws, size_t ws_size,
                              hipStream_t stream) {
    const float* x       = (const float*)d_in[0];
    const float* w_att   = (const float*)d_in[1];
    const float* wk_scale= (const float*)d_in[2];
    const float* wk_trans= (const float*)d_in[3];
    const float* wk_wav  = (const float*)d_in[4];
    const float* wk_base = (const float*)d_in[5];
    const float* fc1_w   = (const float*)d_in[6];
    const float* fc1_b   = (const float*)d_in[7];
    const float* fc2_w   = (const float*)d_in[8];
    const float* fc2_b   = (const float*)d_in[9];
    const int*   eidx    = (const int*)d_in[10];
    const int*   batch   = (const int*)d_in[11];
    float* outp = (float*)d_out;

    float* ws = (float*)d_ws;
    float* h      = ws;                        // 1024*512
    float* agg    = h + N_NODES * H_DIM;       // 1024*512
    float* sagg   = agg + N_NODES * H_DIM;     // 1024*512
    float* vb     = sagg + N_NODES * H_DIM;    // 1024*512
    float* muv    = vb + N_NODES * H_DIM;      // 512
    float* Sv     = muv + 512;                 // 512
    float* mux    = Sv + 512;                  // 1024
    float* Sx     = mux + 1024;                // 1024
    int*   gstart = (int*)(Sx + 1024);         // 16
    int*   gcnt   = gstart + 16;               // 16
    float* pooled = (float*)(gcnt + 16);       // 16*1536
    float* h1     = pooled + B_GRAPHS * FH_DIM;// 16*512
    int*   deg    = (int*)(h1 + B_GRAPHS * H_DIM); // 1024
    int*   estart = deg + N_NODES;             // 1024
    int*   cursor = estart + N_NODES;          // 1024
    int*   elist  = cursor + N_NODES;          // 32768

    const int* src = eidx;
    const int* dst = eidx + E_EDGES;

    k_h<<<(N_NODES * H_DIM) / 256, 256, 0, stream>>>(x, w_att, h);
    k_zero_int<<<N_NODES / 256, 256, 0, stream>>>(deg, N_NODES);
    k_hist<<<E_EDGES / 256, 256, 0, stream>>>(dst, deg);
    k_scan<<<1, N_NODES, 0, stream>>>(deg, estart, cursor);
    k_fill<<<E_EDGES / 256, 256, 0, stream>>>(src, dst, cursor, elist);
    k_gather<<<N_NODES, 256, 0, stream>>>(h, estart, deg, elist, agg, sagg);
    k_zero_f<<<(N_NODES * H_DIM) / 256, 256, 0, stream>>>(vb);
    {
        dim3 grid(N_NODES / TN, H_DIM / TO, ZSPLIT);
        k_wavelet<<<grid, 256, 0, stream>>>(agg, sagg, wk_trans, wk_scale,
                                            wk_wav, wk_base, vb);
    }
    k_colstats<<<H_DIM / 16, 256, 0, stream>>>(vb, H_DIM, 1, muv, Sv);
    k_colstats<<<F_DIM / 16, 256, 0, stream>>>(x, F_DIM, 0, mux, Sx);
    k_ranges<<<1, 256, 0, stream>>>(batch, gstart, gcnt);
    {
        dim3 grid(FH_DIM / 256, B_GRAPHS);
        k_pool<<<grid, 256, 0, stream>>>(x, vb, gstart, gcnt, mux, Sx, muv, Sv, pooled);
    }
    k_fc1<<<(B_GRAPHS * H_DIM * 64) / 256, 256, 0, stream>>>(pooled, fc1_w, fc1_b, h1);
    k_fc2<<<(B_GRAPHS * OUT_DIM * 64 + 255) / 256, 256, 0, stream>>>(h1, fc2_w, fc2_b, outp);
}

// Round 3
// 239.059 us; speedup vs baseline: 1.7611x; 1.1503x over previous
//
#include <hip/hip_runtime.h>
#include <hip/hip_bf16.h>
#include <math.h>

// Problem constants (fixed by setup_inputs)
#define N_NODES 1024
#define F_DIM   1024
#define H_DIM   512
#define E_EDGES 32768
#define B_GRAPHS 16
#define OUT_DIM 10
#define FH_DIM  1536
#define EPS 1e-5f
#define MH_C_F 0.8673250705840776f
#define INV_SQRT2 0.70710678118654752440f

typedef float v2f __attribute__((ext_vector_type(2)));

#if __has_builtin(__builtin_amdgcn_exp2f)
#define EXP2F(x) __builtin_amdgcn_exp2f(x)
#define CEXP (-0.72134752044448170368f)   // -0.5 * log2(e)
#else
#define EXP2F(x) __expf(x)
#define CEXP (-0.5f)
#endif

// ---------------- K1: Haar split + attention gate -> h ----------------
__global__ __launch_bounds__(256) void k_h(const float* __restrict__ x,
                                           const float* __restrict__ watt,
                                           float* __restrict__ h) {
    int idx = blockIdx.x * 256 + threadIdx.x;          // 0 .. N*H-1
    float2 p = ((const float2*)x)[idx];
    float lo = (p.x + p.y) * INV_SQRT2;
    float hi = (p.x - p.y) * INV_SQRT2;
    float t  = lo * watt[0] + hi * watt[1];
    float sc = 1.0f / (1.0f + __expf(-t));
    h[idx] = sc * lo + (1.0f - sc) * hi;
}

// ---------------- zero stats + deg ----------------
__global__ __launch_bounds__(256) void k_zero(float* __restrict__ p) {
    p[blockIdx.x * 256 + threadIdx.x] = 0.0f;
}

// ---------------- edge bucketing (counting sort by dst) ----------------
__global__ __launch_bounds__(256) void k_hist(const int* __restrict__ dst,
                                              int* __restrict__ deg) {
    int e = blockIdx.x * 256 + threadIdx.x;
    atomicAdd(&deg[dst[e]], 1);
}

__global__ __launch_bounds__(1024) void k_scan(const int* __restrict__ deg,
                                               int* __restrict__ start,
                                               int* __restrict__ cursor) {
    __shared__ int sh[N_NODES];
    int t = threadIdx.x;
    int d0 = deg[t];
    sh[t] = d0;
    __syncthreads();
    for (int off = 1; off < N_NODES; off <<= 1) {
        int v = (t >= off) ? sh[t - off] : 0;
        __syncthreads();
        sh[t] += v;
        __syncthreads();
    }
    int excl = sh[t] - d0;
    start[t] = excl;
    cursor[t] = excl;
}

__global__ __launch_bounds__(256) void k_fill(const int* __restrict__ src,
                                              const int* __restrict__ dst,
                                              int* __restrict__ cursor,
                                              int* __restrict__ elist) {
    int e = blockIdx.x * 256 + threadIdx.x;
    int slot = atomicAdd(&cursor[dst[e]], 1);
    elist[slot] = src[e];
}

// ---------------- K2: gather (atomic-free scatter-add) ----------------
__global__ __launch_bounds__(256) void k_gather(const float* __restrict__ h,
                                                const int* __restrict__ start,
                                                const int* __restrict__ deg,
                                                const int* __restrict__ elist,
                                                float* __restrict__ agg) {
    int d = blockIdx.x;
    int t = threadIdx.x;
    int st = start[d], dg = deg[d];
    float a0 = h[d * H_DIM + t];
    float a1 = h[d * H_DIM + t + 256];
    for (int k = 0; k < dg; ++k) {
        int s = elist[st + k];
        a0 += h[s * H_DIM + t];
        a1 += h[s * H_DIM + t + 256];
    }
    agg[d * H_DIM + t]       = a0;
    agg[d * H_DIM + t + 256] = a1;
}

// ---------------- K2b: transpose agg [n][i] -> aggT [i][n], + siluT ----------------
__global__ __launch_bounds__(256) void k_transpose(const float* __restrict__ agg,
                                                   float* __restrict__ aggT,
                                                   float* __restrict__ siluT) {
    __shared__ float tile[64 * 65];
    const int t = threadIdx.x;
    const int n0 = blockIdx.x * 64;
    const int i0 = blockIdx.y * 64;
    #pragma unroll
    for (int v = 0; v < 4; ++v) {
        int flat = v * 256 + t;
        int r = flat >> 4, c4 = flat & 15;
        float4 a = *(const float4*)&agg[(n0 + r) * H_DIM + i0 + c4 * 4];
        tile[(c4 * 4 + 0) * 65 + r] = a.x;
        tile[(c4 * 4 + 1) * 65 + r] = a.y;
        tile[(c4 * 4 + 2) * 65 + r] = a.z;
        tile[(c4 * 4 + 3) * 65 + r] = a.w;
    }
    __syncthreads();
    #pragma unroll
    for (int v = 0; v < 4; ++v) {
        int flat = v * 256 + t;
        int il = flat >> 4, c4 = flat & 15;
        float4 a;
        a.x = tile[il * 65 + c4 * 4 + 0];
        a.y = tile[il * 65 + c4 * 4 + 1];
        a.z = tile[il * 65 + c4 * 4 + 2];
        a.w = tile[il * 65 + c4 * 4 + 3];
        int g = (i0 + il) * N_NODES + n0 + c4 * 4;
        *(float4*)&aggT[g] = a;
        float4 s;
        s.x = a.x / (1.0f + __expf(-a.x));
        s.y = a.y / (1.0f + __expf(-a.y));
        s.z = a.z / (1.0f + __expf(-a.z));
        s.w = a.w / (1.0f + __expf(-a.w));
        *(float4*)&siluT[g] = s;
    }
}

// ---------------- K2c: pack params pk[o][i] = (1/scale, trans/scale, ww, bw) ----------------
__global__ __launch_bounds__(256) void k_prep(const float* __restrict__ scale,
                                              const float* __restrict__ trans,
                                              const float* __restrict__ ww,
                                              const float* __restrict__ bw,
                                              float* __restrict__ pk) {
    int g = blockIdx.x * 256 + threadIdx.x;     // 0 .. 512*512-1
    float iv = 1.0f / scale[g];
    float4 p;
    p.x = iv;
    p.y = trans[g] * iv;
    p.z = ww[g];
    p.w = bw[g];
    ((float4*)pk)[g] = p;
}

// ---------------- K3: fused wavelet + base (packed fp32, z-split partials) ----------------
#define TN 64
#define TO 32
#define KI 16
#define ZSPLIT 8
#define ZLEN (H_DIM / ZSPLIT)   // 64
__global__ __launch_bounds__(256, 8) void k_wavelet(const float* __restrict__ aggT,
                                                    const float* __restrict__ siluT,
                                                    const float* __restrict__ pk,
                                                    float* __restrict__ vbp) {
    __shared__ float sA[KI * TN];        // [i][n]
    __shared__ float sS[KI * TN];        // [i][n]
    __shared__ float sP[TO * KI * 4];    // [o][i][4]

    const int t  = threadIdx.x;
    const int n0 = blockIdx.x * TN;
    const int o0 = blockIdx.y * TO;
    const int z0 = blockIdx.z * ZLEN;
    const int nl = (t & 15) * 4;
    const int ol = (t >> 4) * 2;

    v2f accw[2][2] = {};   // [oo][npair]
    v2f accb[2][2] = {};
    const v2f cexp2 = {CEXP, CEXP};
    const v2f one2  = {1.0f, 1.0f};

    for (int stg = 0; stg < ZLEN / KI; ++stg) {
        const int i0 = z0 + stg * KI;
        __syncthreads();
        // n-side: 16 rows (i) x 64 cols (n); thread t stages row t/16, cols (t%16)*4
        {
            int g = (i0 + (t >> 4)) * N_NODES + n0 + nl;
            *(float4*)&sA[t * 4] = *(const float4*)&aggT[g];
            *(float4*)&sS[t * 4] = *(const float4*)&siluT[g];
        }
        // param side: 32 o x 16 i float4s; 2 chunks
        #pragma unroll
        for (int j = 0; j < 2; ++j) {
            int u = j * 256 + t;             // 0..511
            int o = u >> 4, ii = u & 15;
            ((float4*)sP)[u] = ((const float4*)pk)[(o0 + o) * H_DIM + i0 + ii];
        }
        __syncthreads();
        #pragma unroll 4
        for (int ii = 0; ii < KI; ++ii) {
            float4 a = *(const float4*)&sA[ii * TN + nl];
            float4 s = *(const float4*)&sS[ii * TN + nl];
            v2f a01 = {a.x, a.y}, a23 = {a.z, a.w};
            v2f s01 = {s.x, s.y}, s23 = {s.z, s.w};
            #pragma unroll
            for (int oo = 0; oo < 2; ++oo) {
                float4 p = ((const float4*)sP)[(ol + oo) * KI + ii];
                v2f iv2 = {p.x, p.x};
                v2f tf2 = {p.y, p.y};
                v2f w2  = {p.z, p.z};
                v2f b2  = {p.w, p.w};
                {
                    v2f xs = a01 * iv2 - tf2;
                    v2f x2 = xs * xs;
                    v2f arg = x2 * cexp2;
                    v2f e; e.x = EXP2F(arg.x); e.y = EXP2F(arg.y);
                    v2f tt = e * w2;
                    v2f u2 = one2 - x2;
                    accw[oo][0] += u2 * tt;
                    accb[oo][0] += s01 * b2;
                }
                {
                    v2f xs = a23 * iv2 - tf2;
                    v2f x2 = xs * xs;
                    v2f arg = x2 * cexp2;
                    v2f e; e.x = EXP2F(arg.x); e.y = EXP2F(arg.y);
                    v2f tt = e * w2;
                    v2f u2 = one2 - x2;
                    accw[oo][1] += u2 * tt;
                    accb[oo][1] += s23 * b2;
                }
            }
        }
    }
    float* out = vbp + (size_t)blockIdx.z * (N_NODES * H_DIM);
    #pragma unroll
    for (int nn = 0; nn < 4; ++nn) {
        int pr = nn >> 1, cm = nn & 1;
        float2 o2;
        o2.x = MH_C_F * (cm ? accw[0][pr].y : accw[0][pr].x) + (cm ? accb[0][pr].y : accb[0][pr].x);
        o2.y = MH_C_F * (cm ? accw[1][pr].y : accw[1][pr].x) + (cm ? accb[1][pr].y : accb[1][pr].x);
        *(float2*)&out[(n0 + nl + nn) * H_DIM + o0 + ol] = o2;
    }
}

// ---------------- K4: reduce partials -> vb, + column sum/sumsq ----------------
__global__ __launch_bounds__(256) void k_reduce(const float* __restrict__ vbp,
                                                float* __restrict__ vb,
                                                float* __restrict__ colsum,
                                                float* __restrict__ colsum2) {
    const int b = blockIdx.x;           // 64 blocks: 8 o-strips x 8 n-strips
    const int o0 = (b & 7) * 64;
    const int n0 = (b >> 3) * 128;
    const int t = threadIdx.x;
    const int oc = o0 + (t & 63);
    const int nsub = t >> 6;
    float s = 0.f, s2 = 0.f;
    for (int r = 0; r < 32; ++r) {
        int n = n0 + r * 4 + nsub;
        size_t idx = (size_t)n * H_DIM + oc;
        float v = 0.f;
        #pragma unroll
        for (int z = 0; z < ZSPLIT; ++z) v += vbp[z * (N_NODES * H_DIM) + idx];
        vb[idx] = v;
        s += v; s2 += v * v;
    }
    __shared__ float sh1[256], sh2[256];
    sh1[t] = s; sh2[t] = s2;
    __syncthreads();
    if (t < 64) {
        s  = sh1[t] + sh1[t + 64] + sh1[t + 128] + sh1[t + 192];
        s2 = sh2[t] + sh2[t + 64] + sh2[t + 128] + sh2[t + 192];
        unsafeAtomicAdd(&colsum[o0 + t], s);
        unsafeAtomicAdd(&colsum2[o0 + t], s2);
    }
}

// ---------------- K5: x column stats (coalesced) ----------------
__global__ __launch_bounds__(256) void k_xstats(const float* __restrict__ x,
                                                float* __restrict__ xsum,
                                                float* __restrict__ xsum2) {
    const int n0 = blockIdx.x * 64;     // 16 blocks
    const int t = threadIdx.x;
    float s[4] = {}, s2[4] = {};
    for (int r = 0; r < 64; ++r) {
        #pragma unroll
        for (int ch = 0; ch < 4; ++ch) {
            float v = x[(n0 + r) * F_DIM + ch * 256 + t];
            s[ch] += v; s2[ch] += v * v;
        }
    }
    #pragma unroll
    for (int ch = 0; ch < 4; ++ch) {
        unsafeAtomicAdd(&xsum[ch * 256 + t], s[ch]);
        unsafeAtomicAdd(&xsum2[ch * 256 + t], s2[ch]);
    }
}

// ---------------- K6: finalize BN affine params ----------------
__global__ __launch_bounds__(256) void k_finalize(const float* __restrict__ colsum,
                                                  const float* __restrict__ colsum2,
                                                  const float* __restrict__ xsum,
                                                  const float* __restrict__ xsum2,
                                                  float* __restrict__ muv,
                                                  float* __restrict__ Sv,
                                                  float* __restrict__ mux,
                                                  float* __restrict__ Sx) {
    for (int c = threadIdx.x; c < FH_DIM; c += 256) {
        if (c < H_DIM) {
            float mu  = colsum[c] * (1.0f / N_NODES);
            float var = colsum2[c] * (1.0f / N_NODES) - mu * mu;
            if (var < 0.f) var = 0.f;
            float s1v = 1.0f / sqrtf(var + EPS);
            float v1  = var * s1v * s1v;
            float s2v = 1.0f / sqrtf(v1 + EPS);
            float v2  = v1 * s2v * s2v;
            float s3v = 1.0f / sqrtf(v2 + EPS);
            muv[c] = mu;
            Sv[c]  = s1v * s2v * s3v;
        } else {
            int xc = c - H_DIM;
            float mu  = xsum[xc] * (1.0f / N_NODES);
            float var = xsum2[xc] * (1.0f / N_NODES) - mu * mu;
            if (var < 0.f) var = 0.f;
            mux[xc] = mu;
            Sx[xc]  = 1.0f / sqrtf(var + EPS);
        }
    }
}

// ---------------- K7a: graph ranges (batch is sorted) ----------------
__global__ __launch_bounds__(256) void k_ranges(const int* __restrict__ batch,
                                                int* __restrict__ gstart,
                                                int* __restrict__ gcnt) {
    __shared__ int cnt_sh[B_GRAPHS];
    __shared__ int start_sh[B_GRAPHS];
    int t = threadIdx.x;
    if (t < B_GRAPHS) { cnt_sh[t] = 0; start_sh[t] = 0; }
    __syncthreads();
    for (int n = t; n < N_NODES; n += 256) {
        int b = batch[n];
        atomicAdd(&cnt_sh[b], 1);
        if (n == 0 || batch[n - 1] != b) start_sh[b] = n;
    }
    __syncthreads();
    if (t < B_GRAPHS) { gstart[t] = start_sh[t]; gcnt[t] = cnt_sh[t]; }
}

// ---------------- K7b: pooled[b,c] = (mean_b(col) - mu)*S  (coalesced) ----------------
__global__ __launch_bounds__(256) void k_pool(const float* __restrict__ x,
                                              const float* __restrict__ vb,
                                              const int* __restrict__ gstart,
                                              const int* __restrict__ gcnt,
                                              const float* __restrict__ mux,
                                              const float* __restrict__ Sx,
                                              const float* __restrict__ muv,
                                              const float* __restrict__ Sv,
                                              float* __restrict__ pooled) {
    const int b = blockIdx.x;
    const int t = threadIdx.x;
    const int cnt = gcnt[b], st = gstart[b];
    float acc[6] = {};
    for (int r = 0; r < cnt; ++r) {
        int row = st + r;
        #pragma unroll
        for (int ch = 0; ch < 4; ++ch) acc[ch] += x[row * F_DIM + ch * 256 + t];
        #pragma unroll
        for (int ch = 0; ch < 2; ++ch) acc[4 + ch] += vb[row * H_DIM + ch * 256 + t];
    }
    float ic = (cnt > 0) ? 1.0f / (float)cnt : 0.f;
    #pragma unroll
    for (int ch = 0; ch < 4; ++ch) {
        int c = ch * 256 + t;
        pooled[b * FH_DIM + c] = (acc[ch] * ic - mux[c]) * Sx[c];
    }
    #pragma unroll
    for (int ch = 0; ch < 2; ++ch) {
        int c = ch * 256 + t;
        pooled[b * FH_DIM + F_DIM + c] = (acc[4 + ch] * ic - muv[c]) * Sv[c];
    }
}

// ---------------- K8: h1 = relu(pooled @ fc1_w^T + b1) ----------------
__global__ __launch_bounds__(256) void k_fc1(const float* __restrict__ pooled,
                                             const float* __restrict__ w,
                                             const float* __restrict__ bias,
                                             float* __restrict__ h1) {
    int wid = (blockIdx.x * 256 + threadIdx.x) >> 6;   // 0..8191
    int lane = threadIdx.x & 63;
    int b = wid >> 9, o = wid & 511;
    const float* pr = pooled + b * FH_DIM;
    const float* wr = w + o * FH_DIM;
    float acc = 0.f;
    for (int k = lane; k < FH_DIM; k += 64) acc += pr[k] * wr[k];
    #pragma unroll
    for (int off = 32; off > 0; off >>= 1) acc += __shfl_down(acc, off);
    if (lane == 0) h1[b * H_DIM + o] = fmaxf(acc + bias[o], 0.f);
}

// ---------------- K9: out = h1 @ fc2_w^T + b2 ----------------
__global__ __launch_bounds__(256) void k_fc2(const float* __restrict__ h1,
                                             const float* __restrict__ w,
                                             const float* __restrict__ bias,
                                             float* __restrict__ outp) {
    int wid = (blockIdx.x * 256 + threadIdx.x) >> 6;
    int lane = threadIdx.x & 63;
    if (wid >= B_GRAPHS * OUT_DIM) return;
    int b = wid / OUT_DIM, u = wid % OUT_DIM;
    const float* hr = h1 + b * H_DIM;
    const float* wr = w + u * H_DIM;
    float acc = 0.f;
    for (int k = lane; k < H_DIM; k += 64) acc += hr[k] * wr[k];
    #pragma unroll
    for (int off = 32; off > 0; off >>= 1) acc += __shfl_down(acc, off);
    if (lane == 0) outp[b * OUT_DIM + u] = acc + bias[u];
}

extern "C" void kernel_launch(void* const* d_in, const int* in_sizes, int n_in,
                              void* d_out, int out_size, void* d_ws, size_t ws_size,
                              hipStream_t stream) {
    const float* x       = (const float*)d_in[0];
    const float* w_att   = (const float*)d_in[1];
    const float* wk_scale= (const float*)d_in[2];
    const float* wk_trans= (const float*)d_in[3];
    const float* wk_wav  = (const float*)d_in[4];
    const float* wk_base = (const float*)d_in[5];
    const float* fc1_w   = (const float*)d_in[6];
    const float* fc1_b   = (const float*)d_in[7];
    const float* fc2_w   = (const float*)d_in[8];
    const float* fc2_b   = (const float*)d_in[9];
    const int*   eidx    = (const int*)d_in[10];
    const int*   batch   = (const int*)d_in[11];
    float* outp = (float*)d_out;

    float* ws = (float*)d_ws;
    const int NH = N_NODES * H_DIM;            // 524288
    float* h      = ws;                        // 524288
    float* agg    = h + NH;
    float* aggT   = agg + NH;
    float* siluT  = aggT + NH;
    float* pk     = siluT + NH;                // 1048576
    float* vbp    = pk + 4 * (H_DIM * H_DIM);  // 8*524288
    float* vb     = vbp + (size_t)ZSPLIT * NH;
    float* colsum = vb + NH;                   // 512
    float* colsum2= colsum + 512;              // 512
    float* xsum   = colsum2 + 512;             // 1024
    float* xsum2  = xsum + 1024;               // 1024
    int*   deg    = (int*)(xsum2 + 1024);      // 1024
    int*   estart = deg + N_NODES;
    int*   cursor = estart + N_NODES;
    int*   elist  = cursor + N_NODES;          // 32768
    float* muv    = (float*)(elist + E_EDGES); // 512
    float* Sv     = muv + 512;
    float* mux    = Sv + 512;                  // 1024
    float* Sx     = mux + 1024;
    int*   gstart = (int*)(Sx + 1024);
    int*   gcnt   = gstart + 16;
    float* pooled = (float*)(gcnt + 16);       // 24576
    float* h1     = pooled + B_GRAPHS * FH_DIM;// 8192

    const int* src = eidx;
    const int* dst = eidx + E_EDGES;

    // zero colsum/colsum2/xsum/xsum2 (3072) + deg (1024) — contiguous 4096 floats
    k_zero<<<16, 256, 0, stream>>>(colsum);
    k_h<<<NH / 256, 256, 0, stream>>>(x, w_att, h);
    k_hist<<<E_EDGES / 256, 256, 0, stream>>>(dst, deg);
    k_scan<<<1, N_NODES, 0, stream>>>(deg, estart, cursor);
    k_fill<<<E_EDGES / 256, 256, 0, stream>>>(src, dst, cursor, elist);
    k_prep<<<(H_DIM * H_DIM) / 256, 256, 0, stream>>>(wk_scale, wk_trans, wk_wav, wk_base, pk);
    k_xstats<<<16, 256, 0, stream>>>(x, xsum, xsum2);
    k_gather<<<N_NODES, 256, 0, stream>>>(h, estart, deg, elist, agg);
    {
        dim3 grid(N_NODES / 64, H_DIM / 64);
        k_transpose<<<grid, 256, 0, stream>>>(agg, aggT, siluT);
    }
    {
        dim3 grid(N_NODES / TN, H_DIM / TO, ZSPLIT);
        k_wavelet<<<grid, 256, 0, stream>>>(aggT, siluT, pk, vbp);
    }
    k_reduce<<<64, 256, 0, stream>>>(vbp, vb, colsum, colsum2);
    k_finalize<<<1, 256, 0, stream>>>(colsum, colsum2, xsum, xsum2, muv, Sv, mux, Sx);
    k_ranges<<<1, 256, 0, stream>>>(batch, gstart, gcnt);
    k_pool<<<B_GRAPHS, 256, 0, stream>>>(x, vb, gstart, gcnt, mux, Sx, muv, Sv, pooled);
    k_fc1<<<(B_GRAPHS * H_DIM * 64) / 256, 256, 0, stream>>>(pooled, fc1_w, fc1_b, h1);
    k_fc2<<<(B_GRAPHS * OUT_DIM * 64 + 255) / 256, 256, 0, stream>>>(h1, fc2_w, fc2_b, outp);
}